// Round 11
// baseline (169.247 us; speedup 1.0000x reference)
//
#include <hip/hip_runtime.h>
#include <math.h>

#define B_ 8
#define S_ 2048
#define F_ 1024
#define U_ 256
#define M_ (B_ * S_)   // 16384 rows

typedef __attribute__((ext_vector_type(8))) short bf16x8;
typedef __attribute__((ext_vector_type(4))) float f32x4;
typedef __attribute__((ext_vector_type(16))) float f32x16;
typedef unsigned short ushort_t;

__device__ __forceinline__ unsigned short f2bf(float x) {
    unsigned u = __builtin_bit_cast(unsigned, x);
    unsigned r = (u + 0x7fffu + ((u >> 16) & 1u)) >> 16;   // RNE
    return (unsigned short)r;
}
__device__ __forceinline__ float bf2f(unsigned short b) {
    return __builtin_bit_cast(float, ((unsigned)b) << 16);
}
__device__ __forceinline__ void gload16(const void* g, void* l) {
    __builtin_amdgcn_global_load_lds(
        (const __attribute__((address_space(1))) unsigned int*)g,
        (__attribute__((address_space(3))) unsigned int*)l, 16, 0, 0);
}

// ---------------------------------------------------------------------------
// Kernel 0a: x fp32 [M][F] -> bf16 TRANSPOSED xbt [F/8][M][8] via LDS
// transpose. Both global sides coalesced. Grid (128, 16) x 256 thr.
// ---------------------------------------------------------------------------
__global__ __launch_bounds__(256) void convxt_kernel(
    const float* __restrict__ x, ushort_t* __restrict__ xbt)
{
    __shared__ ushort_t T[8][129][8];   // +1 row pad -> conflict-free writes

    const int t  = threadIdx.x;
    const int r0 = blockIdx.x * 128;
    const int k0 = blockIdx.y * 64;

    #pragma unroll
    for (int i = 0; i < 8; ++i) {
        const int r = i * 16 + (t >> 4);
        const int c = (t & 15) * 4;           // 0,4,...,60
        const float4 v = *reinterpret_cast<const float4*>(
            x + (size_t)(r0 + r) * F_ + k0 + c);
        ushort4 o;
        o.x = f2bf(v.x); o.y = f2bf(v.y); o.z = f2bf(v.z); o.w = f2bf(v.w);
        *reinterpret_cast<ushort4*>(&T[c >> 3][r][c & 7]) = o;
    }
    __syncthreads();
    #pragma unroll
    for (int i = 0; i < 4; ++i) {
        const int ci  = i * 256 + t;
        const int ksl = ci >> 7, r = ci & 127;
        ushort_t* dst = xbt + ((size_t)(blockIdx.y * 8 + ksl) * M_ + r0 + r) * 8;
        *reinterpret_cast<bf16x8*>(dst) =
            *reinterpret_cast<const bf16x8*>(&T[ksl][r][0]);
    }
}

// ---------------------------------------------------------------------------
// Kernel 0b: repack W fp32 [1024][256] -> bf16 hi/lo, k-slice-major:
// Wp[wsel][half][kslice=k/8][n][j=k%8].  3 MB total.  Grid (128, 3) x 256.
// ---------------------------------------------------------------------------
__global__ __launch_bounds__(256) void convw_kernel(
    const float* __restrict__ Wq, const float* __restrict__ Wk,
    const float* __restrict__ Wv, ushort_t* __restrict__ Wp)
{
    const int ks   = blockIdx.x;    // 0..127
    const int wsel = blockIdx.y;    // 0..2
    const float* __restrict__ W = (wsel == 0) ? Wq : (wsel == 1) ? Wk : Wv;
    const int n = threadIdx.x;      // 0..255

    bf16x8 hv, lv;
    #pragma unroll
    for (int j = 0; j < 8; ++j) {
        float v = W[(size_t)(ks * 8 + j) * U_ + n];
        ushort_t h = f2bf(v);
        hv[j] = (short)h;
        lv[j] = (short)f2bf(v - bf2f(h));
    }
    size_t base = (size_t)wsel * 524288;   // 2*128*256*8
    *reinterpret_cast<bf16x8*>(&Wp[base + ((size_t)ks) * 2048 + n * 8]) = hv;
    *reinterpret_cast<bf16x8*>(&Wp[base + ((size_t)(128 + ks)) * 2048 + n * 8]) = lv;
}

// ---------------------------------------------------------------------------
// Kernel 1: projection GEMM (unchanged R10): 2-pass MFMA z = xb*(W_hi+W_lo),
// 128x128 tile, 768 blocks (3/CU), 4 waves 64x64, BK=32, dbuf LDS 48 KB.
// ---------------------------------------------------------------------------
__global__ __launch_bounds__(256, 3) void proj_mfma_kernel(
    const ushort_t* __restrict__ xbt,
    const ushort_t* __restrict__ Wp,
    ushort_t* __restrict__ qh_g, ushort_t* __restrict__ kh_g,
    ushort_t* __restrict__ vth_g)
{
    __shared__ ushort_t As[2][4 * 128 * 8];       // [buf][ksl][row][8]   8 KB/buf
    __shared__ ushort_t Bs[2][2 * 4 * 128 * 8];   // [buf][half][ksl][n][8] 16 KB/buf

    const int orig = blockIdx.x;            // 0..767
    const int xcd  = orig & 7;
    const int i    = orig >> 3;             // 0..95
    const int rt6  = i / 6;
    const int sub  = i - rt6 * 6;
    const int wsel = sub >> 1;
    const int nh   = sub & 1;
    const int row0 = (xcd * 16 + rt6) * 128;
    const int col0 = nh * 128;

    const int tid = threadIdx.x;
    const int l = tid & 63, w = tid >> 6;
    const int wy = w >> 1, wx = w & 1;
    const int m = l & 31, hi = l >> 5;

    const ushort_t* __restrict__ WpB = Wp + (size_t)wsel * 524288;

    f32x16 acc[2][2];
    #pragma unroll
    for (int mr = 0; mr < 2; ++mr)
        #pragma unroll
        for (int nf = 0; nf < 2; ++nf)
            #pragma unroll
            for (int r = 0; r < 16; ++r) acc[mr][nf][r] = 0.f;

    auto stageA = [&](int buf, int ks) {
        #pragma unroll
        for (int it = 0; it < 2; ++it) {
            const int ci = it * 256 + tid;
            const int ksl = ci >> 7, r = ci & 127;
            const ushort_t* src =
                xbt + ((size_t)(ks * 4 + ksl) * M_ + row0 + r) * 8;
            gload16(src, (char*)&As[buf][0] + (size_t)(it * 256 + w * 64) * 16);
        }
    };
    auto stageB = [&](int buf, int ks) {
        #pragma unroll
        for (int it = 0; it < 4; ++it) {
            const int ci = it * 256 + tid;
            const int half = ci >> 9, ksl = (ci >> 7) & 3, n = ci & 127;
            const ushort_t* src = WpB + (size_t)half * 262144
                                  + (size_t)(ks * 4 + ksl) * 2048
                                  + (size_t)(col0 + n) * 8;
            gload16(src, (char*)&Bs[buf][0] + (size_t)(it * 256 + w * 64) * 16);
        }
    };

    stageA(0, 0);
    stageB(0, 0);
    __syncthreads();

    for (int ks = 0; ks < 32; ++ks) {
        const int cur = ks & 1;
        if (ks < 31) { stageA(cur ^ 1, ks + 1); stageB(cur ^ 1, ks + 1); }

        const ushort_t* Ac = &As[cur][0];
        const ushort_t* Bc = &Bs[cur][0];

        #pragma unroll
        for (int g = 0; g < 2; ++g) {
            const int ksl = g * 2 + hi;
            bf16x8 ah[2];
            #pragma unroll
            for (int mr = 0; mr < 2; ++mr)
                ah[mr] = *reinterpret_cast<const bf16x8*>(
                    &Ac[(size_t)(ksl * 128 + wy * 64 + mr * 32 + m) * 8]);
            bf16x8 bh[2], bl[2];
            #pragma unroll
            for (int nf = 0; nf < 2; ++nf) {
                const int nn = wx * 64 + nf * 32 + m;
                bh[nf] = *reinterpret_cast<const bf16x8*>(
                    &Bc[(size_t)(ksl * 128 + nn) * 8]);
                bl[nf] = *reinterpret_cast<const bf16x8*>(
                    &Bc[(size_t)(512 * 8 + (ksl * 128 + nn) * 8)]);
            }
            #pragma unroll
            for (int nf = 0; nf < 2; ++nf)
                #pragma unroll
                for (int mr = 0; mr < 2; ++mr)
                    acc[mr][nf] = __builtin_amdgcn_mfma_f32_32x32x16_bf16(
                        ah[mr], bh[nf], acc[mr][nf], 0, 0, 0);
            #pragma unroll
            for (int nf = 0; nf < 2; ++nf)
                #pragma unroll
                for (int mr = 0; mr < 2; ++mr)
                    acc[mr][nf] = __builtin_amdgcn_mfma_f32_32x32x16_bf16(
                        ah[mr], bl[nf], acc[mr][nf], 0, 0, 0);
        }
        __syncthreads();
    }

    #pragma unroll
    for (int mr = 0; mr < 2; ++mr) {
        const int row_base = row0 + wy * 64 + mr * 32;
        if (wsel < 2) {
            ushort_t* __restrict__ hp = (wsel == 0) ? qh_g : kh_g;
            #pragma unroll
            for (int nf = 0; nf < 2; ++nf) {
                const int u = col0 + wx * 64 + nf * 32 + m;
                #pragma unroll
                for (int reg = 0; reg < 16; ++reg) {
                    const int rl = (reg & 3) + 8 * (reg >> 2) + 4 * hi;
                    hp[(size_t)(row_base + rl) * U_ + u] =
                        f2bf(tanhf(acc[mr][nf][reg]));
                }
            }
        } else {
            const int b     = row0 >> 11;
            const int s_blk = (row0 & 2047) + wy * 64 + mr * 32;
            #pragma unroll
            for (int nf = 0; nf < 2; ++nf) {
                const int u = col0 + wx * 64 + nf * 32 + m;
                #pragma unroll
                for (int rg = 0; rg < 4; ++rg) {
                    ushort4 hv;
                    hv.x = f2bf(tanhf(acc[mr][nf][rg * 4 + 0]));
                    hv.y = f2bf(tanhf(acc[mr][nf][rg * 4 + 1]));
                    hv.z = f2bf(tanhf(acc[mr][nf][rg * 4 + 2]));
                    hv.w = f2bf(tanhf(acc[mr][nf][rg * 4 + 3]));
                    size_t off = ((size_t)b * U_ + u) * S_ + s_blk + 8 * rg + 4 * hi;
                    *reinterpret_cast<ushort4*>(&vth_g[off]) = hv;
                }
            }
        }
    }
}

// ---------------------------------------------------------------------------
// Kernel 2 (R11): flash attention on 32x32x16 MFMA, split-K x nkh.
// Block = 128 q (4 waves x 32 q) x (S_/nkh) keys. Per 32-key tile per wave:
// 16 K-reads + 16 MFMA (QK^T), 16 V-reads + 2 P-reads + 16 MFMA (PV) --
// half the LDS bytes/FLOP of the 16x16 design. V stored [u][32keys] with
// XOR chunk swizzle (uniform min bank load). defer-rescale THR=4, __expf.
// LDS: K 2x16KB + V 2x16KB + P 10KB = 74KB -> 2 blocks/CU (when grid >=512).
// ---------------------------------------------------------------------------
__global__ __launch_bounds__(256, 2) void attn_mfma_kernel(
    const ushort_t* __restrict__ qh_g,
    const ushort_t* __restrict__ kh_g,
    const ushort_t* __restrict__ vth_g,
    float* __restrict__ O0, float* __restrict__ O1,
    float* __restrict__ ml, int nkh)
{
    __shared__ ushort_t Kbuf[2][32 * 256];   // [dbuf][key][u-chunk swz] 32 KB
    __shared__ ushort_t Vbuf[2][256 * 32];   // [dbuf][u][key-chunk swz] 32 KB
    __shared__ ushort_t Pbuf[4][32 * 40];    // [wave][q][32keys+8pad]   10 KB

    const int tid = threadIdx.x;
    const int l  = tid & 63, w = tid >> 6;
    const int q  = l & 31, hi = l >> 5;

    // XCD swizzle: one batch per XCD (16*nkh blocks each)
    const int per_b  = 16 * nkh;
    const int logical = (blockIdx.x & 7) * per_b + (blockIdx.x >> 3);
    const int b  = logical / per_b;
    const int r  = logical - b * per_b;
    const int qt = r / nkh;
    const int kh = r - qt * nkh;
    const int ksz = S_ / nkh;
    const int kb0 = kh * ksz;
    const int qrow0 = b * S_ + qt * 128 + w * 32;

    // preload Q fragments: B-operand, lane (n=q, hi): u = c*16 + hi*8 + j
    bf16x8 qf[16];
    {
        const ushort_t* qb = qh_g + (size_t)(qrow0 + q) * U_ + hi * 8;
        #pragma unroll
        for (int c = 0; c < 16; ++c)
            qf[c] = *reinterpret_cast<const bf16x8*>(qb + c * 16);
    }

    f32x16 O[8];
    #pragma unroll
    for (int ut = 0; ut < 8; ++ut)
        #pragma unroll
        for (int rg = 0; rg < 16; ++rg) O[ut][rg] = 0.f;
    float m_run = -INFINITY, l_run = 0.f;

    auto stage = [&](int buf, int k0) {
        // K: 1024 chunks [key][32 slots], slot s holds global chunk s^(key&7)
        #pragma unroll
        for (int i = 0; i < 4; ++i) {
            int c = w * 256 + i * 64 + l;
            int key = c >> 5, s = c & 31;
            int ss = s ^ (key & 7);
            size_t so = (size_t)(b * S_ + k0 + key) * U_ + ss * 8;
            gload16(kh_g + so, &Kbuf[buf][(w * 256 + i * 64) * 8]);
        }
        // V: 1024 chunks [u][4 slots], slot s holds global key-chunk s^(u&3)
        #pragma unroll
        for (int i = 0; i < 4; ++i) {
            int c = w * 256 + i * 64 + l;
            int u = c >> 2, s = c & 3;
            int ss = s ^ (u & 3);
            size_t so = ((size_t)b * U_ + u) * S_ + k0 + ss * 8;
            gload16(vth_g + so, &Vbuf[buf][(w * 256 + i * 64) * 8]);
        }
    };

    stage(0, kb0);

    const float scale = 0.03125f;   // 1/sqrt(F=1024)
    const int ntile = ksz / 32;

    for (int t = 0; t < ntile; ++t) {
        const int cur = t & 1;
        asm volatile("s_waitcnt vmcnt(0)" ::: "memory");
        __builtin_amdgcn_s_barrier();
        if (t < ntile - 1) stage(cur ^ 1, kb0 + (t + 1) * 32);

        const ushort_t* Kh = Kbuf[cur];
        const ushort_t* Vh = Vbuf[cur];

        // ---- QK^T: S^T[key][q] = sum_c mfma(K-frag(c), Q-frag(c)) ----
        f32x16 Sacc;
        #pragma unroll
        for (int rg = 0; rg < 16; ++rg) Sacc[rg] = 0.f;
        #pragma unroll
        for (int c = 0; c < 16; ++c) {
            // A-frag: lane (m=key=q-slot l&31, hi): u-chunk slot (2c+hi)^(key&7)
            const int key = q;
            const int off = key * 256 + (((2 * c + hi) ^ (key & 7)) * 8);
            bf16x8 kf = *reinterpret_cast<const bf16x8*>(Kh + off);
            Sacc = __builtin_amdgcn_mfma_f32_32x32x16_bf16(kf, qf[c], Sacc, 0, 0, 0);
        }

        // ---- online softmax per q (lane&31); C rows = keys ----
        float tm = Sacc[0] * scale;
        #pragma unroll
        for (int rg = 1; rg < 16; ++rg) tm = fmaxf(tm, Sacc[rg] * scale);
        tm = fmaxf(tm, __shfl_xor(tm, 32));
        const bool defer = __all(tm - m_run <= 4.0f);
        float mn = m_run, f;
        if (!defer) {
            mn = fmaxf(m_run, tm);
            f = __expf(m_run - mn);     // first tile: exp(-inf) = 0
            m_run = mn;
        }
        // P = exp(S*scale - mn), bf16-rounded; su from rounded values
        ushort_t ph[16];
        float su = 0.f;
        #pragma unroll
        for (int rg = 0; rg < 16; ++rg) {
            ph[rg] = f2bf(__expf(Sacc[rg] * scale - mn));
            su += bf2f(ph[rg]);
        }
        su += __shfl_xor(su, 32);

        // ---- write P: lane (q=col, hi) keys {(rg&3)+8*(rg>>2)+4hi} ----
        {
            ushort_t* pr = &Pbuf[w][q * 40];
            #pragma unroll
            for (int grp = 0; grp < 4; ++grp) {
                ushort4 v;
                v.x = ph[grp * 4 + 0]; v.y = ph[grp * 4 + 1];
                v.z = ph[grp * 4 + 2]; v.w = ph[grp * 4 + 3];
                *reinterpret_cast<ushort4*>(pr + grp * 8 + hi * 4) = v;
            }
        }

        if (defer) {
            l_run += su;
        } else {
            l_run = l_run * f + su;
            // rescale O: row q' = (rg&3)+8*(rg>>2)+4hi needs f from lane q'
            #pragma unroll
            for (int rg = 0; rg < 16; ++rg) {
                const int qv = (rg & 3) + 8 * (rg >> 2) + 4 * hi;
                const float fr = __shfl(f, qv);
                #pragma unroll
                for (int ut = 0; ut < 8; ++ut) O[ut][rg] *= fr;
            }
        }

        // ---- PV: O[q][u] += P * V ----
        bf16x8 pf[2];
        #pragma unroll
        for (int kc = 0; kc < 2; ++kc)
            pf[kc] = *reinterpret_cast<const bf16x8*>(
                &Pbuf[w][q * 40 + kc * 16 + hi * 8]);
        #pragma unroll
        for (int ut = 0; ut < 8; ++ut) {
            #pragma unroll
            for (int kc = 0; kc < 2; ++kc) {
                const int u = ut * 32 + q;
                const int off = u * 32 + (((kc * 2 + hi) ^ (u & 3)) * 8);
                bf16x8 vf = *reinterpret_cast<const bf16x8*>(Vh + off);
                O[ut] = __builtin_amdgcn_mfma_f32_32x32x16_bf16(pf[kc], vf, O[ut], 0, 0, 0);
            }
        }
    }

    // ---- epilogue: store UNNORMALIZED O + (m, l) per q-row ----
    float* __restrict__ Op = (kh == 0) ? O0 : (O1 + (size_t)(kh - 1) * M_ * U_);
    #pragma unroll
    for (int ut = 0; ut < 8; ++ut) {
        #pragma unroll
        for (int rg = 0; rg < 16; ++rg) {
            const int qv = (rg & 3) + 8 * (rg >> 2) + 4 * hi;
            Op[(size_t)(qrow0 + qv) * U_ + ut * 32 + q] = O[ut][rg];
        }
    }
    if (hi == 0) {
        ml[((size_t)kh * M_ + qrow0 + q) * 2 + 0] = m_run;
        ml[((size_t)kh * M_ + qrow0 + q) * 2 + 1] = l_run;
    }
}

// ---------------------------------------------------------------------------
// Kernel 3: merge nkh split-K partials (partial 0 lives in `out`).
// ---------------------------------------------------------------------------
__global__ __launch_bounds__(256) void merge_kernel(
    const float* __restrict__ O1, const float* __restrict__ ml,
    float* __restrict__ out, int nkh)
{
    const int tid = threadIdx.x;
    const int row = blockIdx.x * 4 + (tid >> 6);
    const int c   = (tid & 63) * 4;

    float mv[4], lv[4];
    float Mx = -INFINITY;
    for (int j = 0; j < nkh; ++j) {
        mv[j] = ml[((size_t)j * M_ + row) * 2 + 0];
        lv[j] = ml[((size_t)j * M_ + row) * 2 + 1];
        Mx = fmaxf(Mx, mv[j]);
    }
    float denom = 0.f;
    float a[4];
    for (int j = 0; j < nkh; ++j) {
        a[j] = __expf(mv[j] - Mx);
        denom += a[j] * lv[j];
    }
    const float inv = 1.f / denom;

    const size_t off = (size_t)row * U_ + c;
    float4 racc;
    {
        const float4 o0 = *reinterpret_cast<const float4*>(out + off);
        const float s = a[0] * inv;
        racc.x = o0.x * s; racc.y = o0.y * s; racc.z = o0.z * s; racc.w = o0.w * s;
    }
    for (int j = 1; j < nkh; ++j) {
        const float4 oj = *reinterpret_cast<const float4*>(
            O1 + (size_t)(j - 1) * M_ * U_ + off);
        const float s = a[j] * inv;
        racc.x += oj.x * s; racc.y += oj.y * s;
        racc.z += oj.z * s; racc.w += oj.w * s;
    }
    *reinterpret_cast<float4*>(out + off) = racc;
}

extern "C" void kernel_launch(void* const* d_in, const int* in_sizes, int n_in,
                              void* d_out, int out_size, void* d_ws, size_t ws_size,
                              hipStream_t stream)
{
    (void)in_sizes; (void)n_in; (void)out_size;
    const float* x  = (const float*)d_in[0];
    const float* Wq = (const float*)d_in[1];
    const float* Wk = (const float*)d_in[2];
    const float* Wv = (const float*)d_in[3];
    float* out = (float*)d_out;

    ushort_t* ws = (ushort_t*)d_ws;
    const size_t T = (size_t)M_ * U_;        // 4,194,304 elements
    ushort_t* qh_g  = ws;                    //  8 MiB
    ushort_t* kh_g  = ws + T;                //  8 MiB
    ushort_t* vth_g = ws + 2 * T;            //  8 MiB  [B][U][S]
    ushort_t* Wp    = ws + 3 * T;            //  3 MiB  [3][2][128][256][8]
    ushort_t* xbt   = ws + 3 * T + 1572864;  // 32 MiB bf16 x^T (dead after proj)
    // O partials / ml OVERLAY xbt (attn runs after proj consumed xbt)
    float*    O1    = (float*)xbt;           // (nkh-1) x 16.8 MiB partials
    // split-K degree: 4 if ws can hold 3 partials + ml (79.2 MB total), else 2
    const int nkh = (ws_size >= 79167488ull) ? 4 : 2;
    float*    ml    = O1 + (size_t)(nkh - 1) * T;   // [nkh][M][2] fp32

    convxt_kernel<<<dim3(128, 16), 256, 0, stream>>>(x, xbt);
    convw_kernel<<<dim3(128, 3), 256, 0, stream>>>(Wq, Wk, Wv, Wp);

    proj_mfma_kernel<<<dim3(768), 256, 0, stream>>>(
        xbt, Wp, qh_g, kh_g, vth_g);

    attn_mfma_kernel<<<dim3(128 * nkh), 256, 0, stream>>>(
        qh_g, kh_g, vth_g, out, O1, ml, nkh);

    merge_kernel<<<dim3(M_ / 4), 256, 0, stream>>>(O1, ml, out, nkh);
}

// Round 12
// 146.645 us; speedup vs baseline: 1.1541x; 1.1541x over previous
//
#include <hip/hip_runtime.h>
#include <math.h>

#define B_ 8
#define S_ 2048
#define F_ 1024
#define U_ 256
#define M_ (B_ * S_)   // 16384 rows

typedef __attribute__((ext_vector_type(8))) short bf16x8;
typedef __attribute__((ext_vector_type(4))) float f32x4;
typedef __attribute__((ext_vector_type(16))) float f32x16;
typedef unsigned short ushort_t;

__device__ __forceinline__ unsigned short f2bf(float x) {
    unsigned u = __builtin_bit_cast(unsigned, x);
    unsigned r = (u + 0x7fffu + ((u >> 16) & 1u)) >> 16;   // RNE
    return (unsigned short)r;
}
__device__ __forceinline__ float bf2f(unsigned short b) {
    return __builtin_bit_cast(float, ((unsigned)b) << 16);
}
__device__ __forceinline__ void gload16(const void* g, void* l) {
    __builtin_amdgcn_global_load_lds(
        (const __attribute__((address_space(1))) unsigned int*)g,
        (__attribute__((address_space(3))) unsigned int*)l, 16, 0, 0);
}
__device__ __forceinline__ f32x4 zero4() {
    f32x4 v; v[0] = 0.f; v[1] = 0.f; v[2] = 0.f; v[3] = 0.f; return v;
}

// ---------------------------------------------------------------------------
// Kernel 0a: x fp32 [M][F] -> bf16 TRANSPOSED xbt [F/8][M][8] via LDS
// transpose. Both global sides coalesced. Grid (128, 16) x 256 thr.
// ---------------------------------------------------------------------------
__global__ __launch_bounds__(256) void convxt_kernel(
    const float* __restrict__ x, ushort_t* __restrict__ xbt)
{
    __shared__ ushort_t T[8][129][8];   // +1 row pad -> conflict-free writes

    const int t  = threadIdx.x;
    const int r0 = blockIdx.x * 128;
    const int k0 = blockIdx.y * 64;

    #pragma unroll
    for (int i = 0; i < 8; ++i) {
        const int r = i * 16 + (t >> 4);
        const int c = (t & 15) * 4;           // 0,4,...,60
        const float4 v = *reinterpret_cast<const float4*>(
            x + (size_t)(r0 + r) * F_ + k0 + c);
        ushort4 o;
        o.x = f2bf(v.x); o.y = f2bf(v.y); o.z = f2bf(v.z); o.w = f2bf(v.w);
        *reinterpret_cast<ushort4*>(&T[c >> 3][r][c & 7]) = o;
    }
    __syncthreads();
    #pragma unroll
    for (int i = 0; i < 4; ++i) {
        const int ci  = i * 256 + t;
        const int ksl = ci >> 7, r = ci & 127;
        ushort_t* dst = xbt + ((size_t)(blockIdx.y * 8 + ksl) * M_ + r0 + r) * 8;
        *reinterpret_cast<bf16x8*>(dst) =
            *reinterpret_cast<const bf16x8*>(&T[ksl][r][0]);
    }
}

// ---------------------------------------------------------------------------
// Kernel 0b: repack W fp32 [1024][256] -> bf16 hi/lo, k-slice-major:
// Wp[wsel][half][kslice=k/8][n][j=k%8].  3 MB total.  Grid (128, 3) x 256.
// ---------------------------------------------------------------------------
__global__ __launch_bounds__(256) void convw_kernel(
    const float* __restrict__ Wq, const float* __restrict__ Wk,
    const float* __restrict__ Wv, ushort_t* __restrict__ Wp)
{
    const int ks   = blockIdx.x;    // 0..127
    const int wsel = blockIdx.y;    // 0..2
    const float* __restrict__ W = (wsel == 0) ? Wq : (wsel == 1) ? Wk : Wv;
    const int n = threadIdx.x;      // 0..255

    bf16x8 hv, lv;
    #pragma unroll
    for (int j = 0; j < 8; ++j) {
        float v = W[(size_t)(ks * 8 + j) * U_ + n];
        ushort_t h = f2bf(v);
        hv[j] = (short)h;
        lv[j] = (short)f2bf(v - bf2f(h));
    }
    size_t base = (size_t)wsel * 524288;   // 2*128*256*8
    *reinterpret_cast<bf16x8*>(&Wp[base + ((size_t)ks) * 2048 + n * 8]) = hv;
    *reinterpret_cast<bf16x8*>(&Wp[base + ((size_t)(128 + ks)) * 2048 + n * 8]) = lv;
}

// ---------------------------------------------------------------------------
// Kernel 1 (R12): projection GEMM. Q,K: 1-PASS (z = xb*W_hi); V: 2-pass
// (z = xb*(W_hi+W_lo)). 128x128 tile, 768 blocks (3/CU), 4 waves 64x64,
// BK=32, dbuf LDS 48 KB. Q output PRE-SCALED by 1/32 (exact in bf16).
// ---------------------------------------------------------------------------
__global__ __launch_bounds__(256, 3) void proj_mfma_kernel(
    const ushort_t* __restrict__ xbt,
    const ushort_t* __restrict__ Wp,
    ushort_t* __restrict__ qh_g, ushort_t* __restrict__ kh_g,
    ushort_t* __restrict__ vth_g)
{
    __shared__ ushort_t As[2][4 * 128 * 8];       // [buf][ksl][row][8]   8 KB/buf
    __shared__ ushort_t Bs[2][2 * 4 * 128 * 8];   // [buf][half][ksl][n][8] 16 KB/buf

    const int orig = blockIdx.x;            // 0..767
    const int xcd  = orig & 7;
    const int i    = orig >> 3;             // 0..95
    const int rt6  = i / 6;
    const int sub  = i - rt6 * 6;
    const int wsel = sub >> 1;
    const int nh   = sub & 1;
    const int row0 = (xcd * 16 + rt6) * 128;
    const int col0 = nh * 128;
    const bool twopass = (wsel == 2);

    const int tid = threadIdx.x;
    const int l = tid & 63, w = tid >> 6;
    const int wy = w >> 1, wx = w & 1;
    const int m = l & 31, hi = l >> 5;

    const ushort_t* __restrict__ WpB = Wp + (size_t)wsel * 524288;

    f32x16 acc[2][2];
    #pragma unroll
    for (int mr = 0; mr < 2; ++mr)
        #pragma unroll
        for (int nf = 0; nf < 2; ++nf)
            #pragma unroll
            for (int r = 0; r < 16; ++r) acc[mr][nf][r] = 0.f;

    auto stageA = [&](int buf, int ks) {
        #pragma unroll
        for (int it = 0; it < 2; ++it) {
            const int ci = it * 256 + tid;
            const int ksl = ci >> 7, r = ci & 127;
            const ushort_t* src =
                xbt + ((size_t)(ks * 4 + ksl) * M_ + row0 + r) * 8;
            gload16(src, (char*)&As[buf][0] + (size_t)(it * 256 + w * 64) * 16);
        }
    };
    // stage B: hi half always (it 0..1); lo half only for V blocks (it 2..3)
    auto stageB = [&](int buf, int ks) {
        const int nit = twopass ? 4 : 2;
        for (int it = 0; it < nit; ++it) {
            const int ci = it * 256 + tid;
            const int half = ci >> 9, ksl = (ci >> 7) & 3, n = ci & 127;
            const ushort_t* src = WpB + (size_t)half * 262144
                                  + (size_t)(ks * 4 + ksl) * 2048
                                  + (size_t)(col0 + n) * 8;
            gload16(src, (char*)&Bs[buf][0] + (size_t)(it * 256 + w * 64) * 16);
        }
    };

    stageA(0, 0);
    stageB(0, 0);
    __syncthreads();

    for (int ks = 0; ks < 32; ++ks) {
        const int cur = ks & 1;
        if (ks < 31) { stageA(cur ^ 1, ks + 1); stageB(cur ^ 1, ks + 1); }

        const ushort_t* Ac = &As[cur][0];
        const ushort_t* Bc = &Bs[cur][0];

        #pragma unroll
        for (int g = 0; g < 2; ++g) {
            const int ksl = g * 2 + hi;
            bf16x8 ah[2];
            #pragma unroll
            for (int mr = 0; mr < 2; ++mr)
                ah[mr] = *reinterpret_cast<const bf16x8*>(
                    &Ac[(size_t)(ksl * 128 + wy * 64 + mr * 32 + m) * 8]);
            bf16x8 bh[2];
            #pragma unroll
            for (int nf = 0; nf < 2; ++nf) {
                const int nn = wx * 64 + nf * 32 + m;
                bh[nf] = *reinterpret_cast<const bf16x8*>(
                    &Bc[(size_t)(ksl * 128 + nn) * 8]);
            }
            #pragma unroll
            for (int nf = 0; nf < 2; ++nf)
                #pragma unroll
                for (int mr = 0; mr < 2; ++mr)
                    acc[mr][nf] = __builtin_amdgcn_mfma_f32_32x32x16_bf16(
                        ah[mr], bh[nf], acc[mr][nf], 0, 0, 0);
            if (twopass) {
                bf16x8 bl[2];
                #pragma unroll
                for (int nf = 0; nf < 2; ++nf) {
                    const int nn = wx * 64 + nf * 32 + m;
                    bl[nf] = *reinterpret_cast<const bf16x8*>(
                        &Bc[(size_t)(512 * 8 + (ksl * 128 + nn) * 8)]);
                }
                #pragma unroll
                for (int nf = 0; nf < 2; ++nf)
                    #pragma unroll
                    for (int mr = 0; mr < 2; ++mr)
                        acc[mr][nf] = __builtin_amdgcn_mfma_f32_32x32x16_bf16(
                            ah[mr], bl[nf], acc[mr][nf], 0, 0, 0);
            }
        }
        __syncthreads();
    }

    // ---- epilogue: tanh (+1/32 pre-scale for Q), bf16, store ----
    // C layout (32x32): col = lane&31, row = (reg&3) + 8*(reg>>2) + 4*(lane>>5)
    const float oscale = (wsel == 0) ? 0.03125f : 1.0f;   // exact 2^-5
    #pragma unroll
    for (int mr = 0; mr < 2; ++mr) {
        const int row_base = row0 + wy * 64 + mr * 32;
        if (wsel < 2) {
            ushort_t* __restrict__ hp = (wsel == 0) ? qh_g : kh_g;
            #pragma unroll
            for (int nf = 0; nf < 2; ++nf) {
                const int u = col0 + wx * 64 + nf * 32 + m;
                #pragma unroll
                for (int reg = 0; reg < 16; ++reg) {
                    const int rl = (reg & 3) + 8 * (reg >> 2) + 4 * hi;
                    hp[(size_t)(row_base + rl) * U_ + u] =
                        f2bf(tanhf(acc[mr][nf][reg]) * oscale);
                }
            }
        } else {
            const int b     = row0 >> 11;
            const int s_blk = (row0 & 2047) + wy * 64 + mr * 32;
            #pragma unroll
            for (int nf = 0; nf < 2; ++nf) {
                const int u = col0 + wx * 64 + nf * 32 + m;
                #pragma unroll
                for (int rg = 0; rg < 4; ++rg) {
                    ushort4 hv;
                    hv.x = f2bf(tanhf(acc[mr][nf][rg * 4 + 0]));
                    hv.y = f2bf(tanhf(acc[mr][nf][rg * 4 + 1]));
                    hv.z = f2bf(tanhf(acc[mr][nf][rg * 4 + 2]));
                    hv.w = f2bf(tanhf(acc[mr][nf][rg * 4 + 3]));
                    size_t off = ((size_t)b * U_ + u) * S_ + s_blk + 8 * rg + 4 * hi;
                    *reinterpret_cast<ushort4*>(&vth_g[off]) = hv;
                }
            }
        }
    }
}

// ---------------------------------------------------------------------------
// Kernel 2 (R12 = R10 structure): flash attention 16x16 MFMA, split-K x2,
// __expf + defer-rescale THR=4. Q pre-scaled by 1/32 -> no score scaling.
// ---------------------------------------------------------------------------
__global__ __launch_bounds__(256, 2) void attn_mfma_kernel(
    const ushort_t* __restrict__ qh_g,
    const ushort_t* __restrict__ kh_g,
    const ushort_t* __restrict__ vth_g,
    float* __restrict__ O0, float* __restrict__ O1,
    float* __restrict__ ml)
{
    __shared__ ushort_t Kbuf[2][32 * 256];   // [dbuf][key][u] swizzled (32 KB)
    __shared__ ushort_t Vbuf[2][256 * 40];   // [dbuf][u][32+8pad]     (40 KB)
    __shared__ ushort_t Pbuf[4][512];        // [wave][kg][q][8]        (4 KB)

    const int tid = threadIdx.x;
    const int l  = tid & 63, w = tid >> 6;
    const int kq = l & 15,  g = l >> 4;

    // XCD swizzle: each XCD owns one batch (64 blocks: 32 q-tiles x 2 halves)
    const int logical = (blockIdx.x & 7) * 64 + (blockIdx.x >> 3);
    const int b     = logical >> 6;
    const int qb    = (logical >> 1) & 31;
    const int khalf = logical & 1;
    const int qrow0 = b * S_ + qb * 64 + w * 16;
    const int kb0   = khalf * 1024;           // key offset within batch

    // preload Q fragments (B-operand: n = lane&15 -> q, k = u = g*8+j)
    bf16x8 qh[8];
    {
        const ushort_t* qbh = qh_g + (size_t)(qrow0 + kq) * U_;
        #pragma unroll
        for (int us = 0; us < 8; ++us)
            qh[us] = *reinterpret_cast<const bf16x8*>(qbh + us * 32 + g * 8);
    }

    f32x4 O[16];
    #pragma unroll
    for (int nt = 0; nt < 16; ++nt) O[nt] = zero4();
    float m_run = -INFINITY, l_run = 0.f;

    auto stage = [&](int buf, int k0) {
        #pragma unroll
        for (int i = 0; i < 4; ++i) {
            int c = w * 256 + i * 64 + l;
            int key = c >> 5, uc = c & 31;
            int ucs = uc ^ (key & 7);                       // pre-swizzled source
            size_t so = (size_t)(b * S_ + k0 + key) * U_ + ucs * 8;
            gload16(kh_g + so, &Kbuf[buf][(w * 256 + i * 64) * 8]);
        }
        #pragma unroll
        for (int i = 0; i < 5; ++i) {
            int c = w * 320 + i * 64 + l;
            int u = (c * 52429) >> 18;                      // c / 5
            int kc = c - u * 5;
            size_t so = ((size_t)b * U_ + u) * S_ + k0 + kc * 8;
            const ushort_t* sh = (kc < 4) ? (vth_g + so) : vth_g;
            gload16(sh, &Vbuf[buf][(w * 320 + i * 64) * 8]);
        }
    };

    stage(0, kb0);

    for (int t = 0; t < 32; ++t) {
        const int cur = t & 1;
        asm volatile("s_waitcnt vmcnt(0)" ::: "memory");
        __builtin_amdgcn_s_barrier();
        if (t < 31) stage(cur ^ 1, kb0 + (t + 1) * 32);

        const ushort_t* Kh = Kbuf[cur];
        const ushort_t* Vh = Vbuf[cur];

        // ---- QK^T as S^T = K * Q^T (Q pre-scaled by 1/32) ----
        f32x4 s0 = zero4(), s1 = zero4();
        #pragma unroll
        for (int us = 0; us < 8; ++us) {
            int off0 = kq * 256 + ((us * 32 + g * 8) ^ ((kq & 7) * 8));
            bf16x8 k0h = *reinterpret_cast<const bf16x8*>(Kh + off0);
            s0 = __builtin_amdgcn_mfma_f32_16x16x32_bf16(k0h, qh[us], s0, 0, 0, 0);
            int off1 = off0 + 16 * 256;                     // key+16
            bf16x8 k1h = *reinterpret_cast<const bf16x8*>(Kh + off1);
            s1 = __builtin_amdgcn_mfma_f32_16x16x32_bf16(k1h, qh[us], s1, 0, 0, 0);
        }

        // ---- online softmax (per q = lane&15), defer-rescale THR=4 ----
        float tm = fmaxf(fmaxf(fmaxf(s0[0], s0[1]), fmaxf(s0[2], s0[3])),
                         fmaxf(fmaxf(s1[0], s1[1]), fmaxf(s1[2], s1[3])));
        tm = fmaxf(tm, __shfl_xor(tm, 16));
        tm = fmaxf(tm, __shfl_xor(tm, 32));
        const bool defer = __all(tm - m_run <= 4.0f);
        float mn = m_run, f;
        if (!defer) {
            mn = fmaxf(m_run, tm);
            f = __expf(m_run - mn);     // first tile: exp(-inf) = 0
            m_run = mn;
        }
        ushort_t ph0[4], ph1[4];
        float su = 0.f;
        #pragma unroll
        for (int r = 0; r < 4; ++r) {
            ph0[r] = f2bf(__expf(s0[r] - mn)); su += bf2f(ph0[r]);
        }
        #pragma unroll
        for (int r = 0; r < 4; ++r) {
            ph1[r] = f2bf(__expf(s1[r] - mn)); su += bf2f(ph1[r]);
        }
        su += __shfl_xor(su, 16);
        su += __shfl_xor(su, 32);

        // ---- write P into PV-A-fragment layout [kg][q][8] ----
        {
            ushort4 a, c;
            a.x = ph0[0]; a.y = ph0[1]; a.z = ph0[2]; a.w = ph0[3];
            c.x = ph1[0]; c.y = ph1[1]; c.z = ph1[2]; c.w = ph1[3];
            int pw0 = ((g >> 1)) * 128 + kq * 8 + (g & 1) * 4;        // kg 0|1
            int pw1 = (2 + (g >> 1)) * 128 + kq * 8 + (g & 1) * 4;    // kg 2|3
            *reinterpret_cast<ushort4*>(&Pbuf[w][pw0]) = a;
            *reinterpret_cast<ushort4*>(&Pbuf[w][pw1]) = c;
        }

        if (defer) {
            l_run += su;
        } else {
            l_run = l_run * f + su;
            float fr0 = __shfl(f, g * 4 + 0), fr1 = __shfl(f, g * 4 + 1);
            float fr2 = __shfl(f, g * 4 + 2), fr3 = __shfl(f, g * 4 + 3);
            #pragma unroll
            for (int nt = 0; nt < 16; ++nt) {
                O[nt][0] *= fr0; O[nt][1] *= fr1;
                O[nt][2] *= fr2; O[nt][3] *= fr3;
            }
        }

        // ---- PV: O += P * V ----
        bf16x8 pa_h = *reinterpret_cast<const bf16x8*>(&Pbuf[w][g * 128 + kq * 8]);
        #pragma unroll
        for (int nt = 0; nt < 16; ++nt) {
            int vo = (nt * 16 + kq) * 40 + g * 8;
            bf16x8 vh = *reinterpret_cast<const bf16x8*>(Vh + vo);
            O[nt] = __builtin_amdgcn_mfma_f32_16x16x32_bf16(pa_h, vh, O[nt], 0, 0, 0);
        }
    }

    // ---- epilogue: store UNNORMALIZED O + (m, l) per row ----
    float* __restrict__ Op = khalf ? O1 : O0;
    #pragma unroll
    for (int nt = 0; nt < 16; ++nt) {
        const int col = nt * 16 + kq;
        Op[(size_t)(qrow0 + g * 4 + 0) * U_ + col] = O[nt][0];
        Op[(size_t)(qrow0 + g * 4 + 1) * U_ + col] = O[nt][1];
        Op[(size_t)(qrow0 + g * 4 + 2) * U_ + col] = O[nt][2];
        Op[(size_t)(qrow0 + g * 4 + 3) * U_ + col] = O[nt][3];
    }
    if (g == 0) {   // lanes 0..15: one per q-row of this wave
        ml[((size_t)khalf * M_ + qrow0 + kq) * 2 + 0] = m_run;
        ml[((size_t)khalf * M_ + qrow0 + kq) * 2 + 1] = l_run;
    }
}

// ---------------------------------------------------------------------------
// Kernel 3: merge the two split-K partials.
// ---------------------------------------------------------------------------
__global__ __launch_bounds__(256) void merge_kernel(
    const float* __restrict__ O1, const float* __restrict__ ml,
    float* __restrict__ out)
{
    const int tid = threadIdx.x;
    const int row = blockIdx.x * 4 + (tid >> 6);
    const int c   = (tid & 63) * 4;

    const float m0 = ml[(size_t)row * 2 + 0];
    const float l0 = ml[(size_t)row * 2 + 1];
    const float m1 = ml[((size_t)M_ + row) * 2 + 0];
    const float l1 = ml[((size_t)M_ + row) * 2 + 1];
    const float Mx = fmaxf(m0, m1);
    float a0 = __expf(m0 - Mx), a1 = __expf(m1 - Mx);
    const float inv = 1.f / (a0 * l0 + a1 * l1);
    a0 *= inv; a1 *= inv;

    const size_t off = (size_t)row * U_ + c;
    const float4 o0 = *reinterpret_cast<const float4*>(out + off);
    const float4 o1 = *reinterpret_cast<const float4*>(O1 + off);
    float4 r;
    r.x = o0.x * a0 + o1.x * a1;
    r.y = o0.y * a0 + o1.y * a1;
    r.z = o0.z * a0 + o1.z * a1;
    r.w = o0.w * a0 + o1.w * a1;
    *reinterpret_cast<float4*>(out + off) = r;
}

extern "C" void kernel_launch(void* const* d_in, const int* in_sizes, int n_in,
                              void* d_out, int out_size, void* d_ws, size_t ws_size,
                              hipStream_t stream)
{
    (void)in_sizes; (void)n_in; (void)out_size; (void)ws_size;
    const float* x  = (const float*)d_in[0];
    const float* Wq = (const float*)d_in[1];
    const float* Wk = (const float*)d_in[2];
    const float* Wv = (const float*)d_in[3];
    float* out = (float*)d_out;

    ushort_t* ws = (ushort_t*)d_ws;
    const size_t T = (size_t)M_ * U_;        // 4,194,304 elements
    ushort_t* qh_g  = ws;                    //  8 MiB
    ushort_t* kh_g  = ws + T;                //  8 MiB
    ushort_t* vth_g = ws + 2 * T;            //  8 MiB  [B][U][S]
    ushort_t* Wp    = ws + 3 * T;            //  3 MiB  [3][2][128][256][8]
    ushort_t* xbt   = ws + 3 * T + 1572864;  // 32 MiB bf16 x^T (dead after proj)
    // O1/ml OVERLAY xbt: written by attn only after proj has consumed xbt.
    float*    O1    = (float*)xbt;           // 16.8 MiB partial
    float*    ml    = O1 + T;                // 0.26 MiB [2][M][2]

    convxt_kernel<<<dim3(128, 16), 256, 0, stream>>>(x, xbt);
    convw_kernel<<<dim3(128, 3), 256, 0, stream>>>(Wq, Wk, Wv, Wp);

    proj_mfma_kernel<<<dim3(768), 256, 0, stream>>>(
        xbt, Wp, qh_g, kh_g, vth_g);

    attn_mfma_kernel<<<dim3(512), 256, 0, stream>>>(
        qh_g, kh_g, vth_g, out, O1, ml);

    merge_kernel<<<dim3(M_ / 4), 256, 0, stream>>>(O1, ml, out);
}